// Round 1
// baseline (613.641 us; speedup 1.0000x reference)
//
#include <hip/hip_runtime.h>
#include <math.h>

#define BB 32
#define TT 2048
#define DD 1024

#define EROWS_PER_WAVE  8
#define EROWS_PER_BLOCK 32              // 4 waves * 8 rows
#define CCHUNK 64
#define NCHUNK (TT / CCHUNK)            // 32 chunks

// fast tanh via hardware exp: tanh(x) = 1 - 2/(e^{2x}+1)
// exact at +-inf saturation; |err| ~1e-7 mid-range. Threshold is 2.3e-2.
__device__ __forceinline__ float fast_tanh(float x) {
    float e = __expf(2.0f * x);
    return 1.0f - __fdividef(2.0f, e + 1.0f);
}

// ---------------- kernel 1: energies[b,t] = v . tanh(keys + query + wf) ----
// One WAVE per row, 8 rows per wave (32 rows / 256-thr block).
// query/v live in registers for the whole block (16+16 VGPR); per row we
// issue all 8 row loads (k,w x 4 float4 = 128 B/lane) before any use, so
// each CU keeps ~10x more bytes in flight than the 1-row-per-block version.
// Reduce is pure shfl_xor — no LDS, no barrier. Rows t >= len[b] skipped
// (softmax writes exact 0 there).
__global__ __launch_bounds__(256) void energies_kernel(
    const float* __restrict__ keys, const float* __restrict__ query,
    const float* __restrict__ wf, const float* __restrict__ v,
    const int* __restrict__ lenp, float* __restrict__ eout)
{
    const int b = blockIdx.y;
    const int L = lenp[b];
    const int t0 = blockIdx.x * EROWS_PER_BLOCK;
    if (t0 >= L) return;

    const int lane = threadIdx.x & 63;
    const int wv   = threadIdx.x >> 6;
    const int d0   = lane * 4;           // + j*256 covers d = 0..1023

    float4 q[4], vv[4];
    #pragma unroll
    for (int j = 0; j < 4; j++) {
        q[j]  = *(const float4*)(query + (size_t)b * DD + j * 256 + d0);
        vv[j] = *(const float4*)(v + j * 256 + d0);
    }

    const int tBeg = t0 + wv * EROWS_PER_WAVE;
    const int tEnd = min(tBeg + EROWS_PER_WAVE, L);
    for (int t = tBeg; t < tEnd; t++) {
        const size_t row = ((size_t)b * TT + t) * DD;
        float4 k[4], w[4];
        #pragma unroll
        for (int j = 0; j < 4; j++) {     // 8 independent loads in flight
            k[j] = *(const float4*)(keys + row + j * 256 + d0);
            w[j] = *(const float4*)(wf   + row + j * 256 + d0);
        }
        float s = 0.0f;
        #pragma unroll
        for (int j = 0; j < 4; j++) {
            s += vv[j].x * fast_tanh(k[j].x + q[j].x + w[j].x);
            s += vv[j].y * fast_tanh(k[j].y + q[j].y + w[j].y);
            s += vv[j].z * fast_tanh(k[j].z + q[j].z + w[j].z);
            s += vv[j].w * fast_tanh(k[j].w + q[j].w + w[j].w);
        }
        #pragma unroll
        for (int off = 32; off > 0; off >>= 1)
            s += __shfl_xor(s, off, 64);
        if (lane == 0) eout[(size_t)b * TT + t] = s;
    }
}

// ---------------- kernel 2: masked softmax over T, in place ---------------
// one block (256 thr) per b; 8 elements per thread. Writes exact 0 for t>=L.
__global__ __launch_bounds__(256) void softmax_kernel(
    const int* __restrict__ lenp, float* __restrict__ wrow_all)
{
    const int b = blockIdx.x;
    const int L = lenp[b];
    float* wrow = wrow_all + (size_t)b * TT;

    float e[8];
    float m = -INFINITY;
    #pragma unroll
    for (int i = 0; i < 8; i++) {
        const int t = threadIdx.x + i * 256;
        e[i] = (t < L) ? wrow[t] : -INFINITY;
        m = fmaxf(m, e[i]);
    }
    #pragma unroll
    for (int off = 1; off < 64; off <<= 1) m = fmaxf(m, __shfl_xor(m, off, 64));
    __shared__ float redm[4];
    const int wv = threadIdx.x >> 6;
    if ((threadIdx.x & 63) == 0) redm[wv] = m;
    __syncthreads();
    m = fmaxf(fmaxf(redm[0], redm[1]), fmaxf(redm[2], redm[3]));

    float s = 0.0f;
    #pragma unroll
    for (int i = 0; i < 8; i++) {
        e[i] = (e[i] == -INFINITY) ? 0.0f : __expf(e[i] - m);
        s += e[i];
    }
    #pragma unroll
    for (int off = 1; off < 64; off <<= 1) s += __shfl_xor(s, off, 64);
    __shared__ float reds[4];
    if ((threadIdx.x & 63) == 0) reds[wv] = s;
    __syncthreads();
    s = reds[0] + reds[1] + reds[2] + reds[3];
    const float inv = 1.0f / s;

    #pragma unroll
    for (int i = 0; i < 8; i++)
        wrow[threadIdx.x + i * 256] = e[i] * inv;   // exact 0 for masked t
}

// ---------------- kernel 3a: per-chunk partial contexts into d_ws ---------
// grid (NCHUNK, BB); block covers full D (float4/thread). Chunk c writes
// partial[c][b][:]. Chunks fully past len[b] write NOTHING — the reducer
// only sums ceil(L/CCHUNK) chunks, so poisoned ws is never read.
// Deterministic, no atomics, no memset.
__global__ __launch_bounds__(256) void context_partial_kernel(
    const float* __restrict__ value, const float* __restrict__ weights,
    const int* __restrict__ lenp, float* __restrict__ partial)
{
    const int b = blockIdx.y;
    const int L = lenp[b];
    const int c = blockIdx.x;
    const int t0 = c * CCHUNK;
    if (t0 >= L) return;
    const int tend = min(t0 + CCHUNK, L);
    const int d = threadIdx.x * 4;

    __shared__ float wsh[CCHUNK];
    if (threadIdx.x < CCHUNK) {
        const int t = t0 + threadIdx.x;
        wsh[threadIdx.x] = (t < L) ? weights[(size_t)b * TT + t] : 0.0f;
    }
    __syncthreads();

    float4 acc = make_float4(0.f, 0.f, 0.f, 0.f);
    #pragma unroll 4
    for (int t = t0; t < tend; t++) {
        const float wt = wsh[t - t0];
        const float4 v4 = *(const float4*)(value + ((size_t)b * TT + t) * DD + d);
        acc.x += wt * v4.x; acc.y += wt * v4.y;
        acc.z += wt * v4.z; acc.w += wt * v4.w;
    }
    *(float4*)(partial + ((size_t)c * BB + b) * DD + d) = acc;
}

// ---------------- kernel 3b: context[b,:] = sum_c partial[c][b][:] --------
__global__ __launch_bounds__(256) void context_reduce_kernel(
    const float* __restrict__ partial, const int* __restrict__ lenp,
    float* __restrict__ context)
{
    const int b = blockIdx.x;
    const int nch = (lenp[b] + CCHUNK - 1) / CCHUNK;
    const int d = threadIdx.x * 4;
    float4 acc = make_float4(0.f, 0.f, 0.f, 0.f);
    for (int c = 0; c < nch; c++) {
        const float4 p = *(const float4*)(partial + ((size_t)c * BB + b) * DD + d);
        acc.x += p.x; acc.y += p.y; acc.z += p.z; acc.w += p.w;
    }
    *(float4*)(context + (size_t)b * DD + d) = acc;
}

// ---------------- fallback (ws too small): old atomic context -------------
__global__ __launch_bounds__(256) void context_atomic_kernel(
    const float* __restrict__ value, const float* __restrict__ weights,
    const int* __restrict__ lenp, float* __restrict__ context)
{
    const int b = blockIdx.y;
    const int L = lenp[b];
    const int t0 = blockIdx.x * CCHUNK;
    if (t0 >= L) return;
    const int tend = min(t0 + CCHUNK, L);
    const int d = threadIdx.x * 4;

    float4 acc = make_float4(0.f, 0.f, 0.f, 0.f);
    for (int t = t0; t < tend; t++) {
        const float w = weights[(size_t)b * TT + t];
        const float4 v4 = *(const float4*)(value + ((size_t)b * TT + t) * DD + d);
        acc.x += w * v4.x; acc.y += w * v4.y;
        acc.z += w * v4.z; acc.w += w * v4.w;
    }
    float* dst = context + (size_t)b * DD + d;
    atomicAdd(dst + 0, acc.x);
    atomicAdd(dst + 1, acc.y);
    atomicAdd(dst + 2, acc.z);
    atomicAdd(dst + 3, acc.w);
}

extern "C" void kernel_launch(void* const* d_in, const int* in_sizes, int n_in,
                              void* d_out, int out_size, void* d_ws, size_t ws_size,
                              hipStream_t stream) {
    const float* keys  = (const float*)d_in[0];
    const float* value = (const float*)d_in[1];
    const float* query = (const float*)d_in[2];
    const float* wf    = (const float*)d_in[3];
    const float* v     = (const float*)d_in[4];
    const int*   lenp  = (const int*)d_in[5];

    float* out      = (float*)d_out;
    float* context  = out;               // [B, D]
    float* weights  = out + BB * DD;     // [B, T] (weights[:,:,None] flattened)

    energies_kernel<<<dim3(TT / EROWS_PER_BLOCK, BB), 256, 0, stream>>>(
        keys, query, wf, v, lenp, weights);
    softmax_kernel<<<BB, 256, 0, stream>>>(lenp, weights);

    const size_t need = (size_t)NCHUNK * BB * DD * sizeof(float);   // 4 MiB
    if (d_ws != nullptr && ws_size >= need) {
        float* partial = (float*)d_ws;
        context_partial_kernel<<<dim3(NCHUNK, BB), 256, 0, stream>>>(
            value, weights, lenp, partial);
        context_reduce_kernel<<<BB, 256, 0, stream>>>(partial, lenp, context);
    } else {
        hipMemsetAsync(context, 0, (size_t)BB * DD * sizeof(float), stream);
        context_atomic_kernel<<<dim3(NCHUNK, BB), 256, 0, stream>>>(
            value, weights, lenp, context);
    }
}